// Round 1
// baseline (253.431 us; speedup 1.0000x reference)
//
#include <hip/hip_runtime.h>
#include <stdint.h>

typedef __attribute__((ext_vector_type(8))) short s16x8;
typedef __attribute__((ext_vector_type(4))) float f32x4;

#define DIM 1024
#define NQ 4096
#define NDOC 8192

__device__ __forceinline__ unsigned short f2bf(float f) {
    unsigned int u = __builtin_bit_cast(unsigned int, f);
    u += 0x7FFFu + ((u >> 16) & 1u);   // RNE
    return (unsigned short)(u >> 16);
}
__device__ __forceinline__ float bf2f(unsigned int s) {
    unsigned int u = (s & 0xFFFFu) << 16;
    return __builtin_bit_cast(float, u);
}

// ---------------- kernel 1: L2-normalize rows, cast to bf16 ----------------
// one block per row (256 threads, 4 floats/thread); rows 0..4095 -> qn,
// 4096..8191 -> dn[0..4095] (positives), 8192..12287 -> dn[4096..8191] (negatives)
__global__ __launch_bounds__(256) void normalize_kernel(
    const float* __restrict__ q, const float* __restrict__ pos,
    const float* __restrict__ neg, unsigned short* __restrict__ qn,
    unsigned short* __restrict__ dn) {
    int row = blockIdx.x;
    const float* src;
    unsigned short* dst;
    if (row < 4096) { src = q + (size_t)row * DIM; dst = qn + (size_t)row * DIM; }
    else if (row < 8192) { src = pos + (size_t)(row - 4096) * DIM; dst = dn + (size_t)(row - 4096) * DIM; }
    else { src = neg + (size_t)(row - 8192) * DIM; dst = dn + (size_t)(row - 4096) * DIM; }
    int t = threadIdx.x;
    float4 v = reinterpret_cast<const float4*>(src)[t];
    float ss = v.x * v.x + v.y * v.y + v.z * v.z + v.w * v.w;
#pragma unroll
    for (int off = 32; off > 0; off >>= 1) ss += __shfl_xor(ss, off, 64);
    __shared__ float wsum[4];
    if ((t & 63) == 0) wsum[t >> 6] = ss;
    __syncthreads();
    float tot = wsum[0] + wsum[1] + wsum[2] + wsum[3];
    float inv = rsqrtf(tot);   // norms ~32, EPS=1e-8 irrelevant
    uint2 o;
    o.x = (unsigned)f2bf(v.x * inv) | ((unsigned)f2bf(v.y * inv) << 16);
    o.y = (unsigned)f2bf(v.z * inv) | ((unsigned)f2bf(v.w * inv) << 16);
    reinterpret_cast<uint2*>(dst)[t] = o;
}

// ---------------- kernel 2: GEMM + fused exp-sum per row ----------------
// scores = 20 * Qn . Dn^T ; rowsum[i] += sum_j exp(scores[i][j] - 20)
// 128x128 tile per WG, 4 waves (2x2), each wave 64x64 via 4x4 16x16x32 MFMA.
#define GLOAD_LDS(g, l) __builtin_amdgcn_global_load_lds( \
    (const __attribute__((address_space(1))) void*)(g),   \
    (__attribute__((address_space(3))) void*)(l), 16, 0, 0)

__global__ __launch_bounds__(256) void gemm_lse_kernel(
    const unsigned short* __restrict__ qn, const unsigned short* __restrict__ dn,
    float* __restrict__ rowsum) {
    __shared__ unsigned short As[128][32];   // 8 KB
    __shared__ unsigned short Bs[128][32];   // 8 KB
    const int t = threadIdx.x;
    const int lane = t & 63;
    const int wave = t >> 6;
    const int wr = wave >> 1, wc = wave & 1;
    const int lr = lane & 15, lk = lane >> 4;
    const int brow = blockIdx.y, bcol = blockIdx.x;
    const int srow = t >> 2;           // 0..63
    const int scol = (t & 3) * 8;      // 0,8,16,24

    const unsigned short* aSrc = qn + ((size_t)brow * 128 + srow) * DIM + scol;
    const unsigned short* bSrc = dn + ((size_t)bcol * 128 + srow) * DIM + scol;

    f32x4 acc[4][4] = {};
    for (int kt = 0; kt < DIM; kt += 32) {
        GLOAD_LDS(aSrc + kt,            &As[srow][scol]);
        GLOAD_LDS(aSrc + kt + 64 * DIM, &As[srow + 64][scol]);
        GLOAD_LDS(bSrc + kt,            &Bs[srow][scol]);
        GLOAD_LDS(bSrc + kt + 64 * DIM, &Bs[srow + 64][scol]);
        __syncthreads();
        s16x8 aF[4], bF[4];
#pragma unroll
        for (int m = 0; m < 4; ++m)
            aF[m] = *reinterpret_cast<const s16x8*>(&As[wr * 64 + m * 16 + lr][lk * 8]);
#pragma unroll
        for (int n = 0; n < 4; ++n)
            bF[n] = *reinterpret_cast<const s16x8*>(&Bs[wc * 64 + n * 16 + lr][lk * 8]);
#pragma unroll
        for (int m = 0; m < 4; ++m)
#pragma unroll
            for (int n = 0; n < 4; ++n)
                acc[m][n] = __builtin_amdgcn_mfma_f32_16x16x32_bf16(aF[m], bF[n], acc[m][n], 0, 0, 0);
        __syncthreads();
    }

    // epilogue: exp(20*acc - 20), reduce over this wave's 64 cols per row,
    // atomicAdd into rowsum. C/D layout: col = lane&15, row = (lane>>4)*4 + j.
#pragma unroll
    for (int m = 0; m < 4; ++m) {
#pragma unroll
        for (int j = 0; j < 4; ++j) {
            float r = 0.f;
#pragma unroll
            for (int n = 0; n < 4; ++n) {
                float s = 20.f * acc[m][n][j] - 20.f;
                r += __expf(s);
            }
#pragma unroll
            for (int off = 1; off < 16; off <<= 1) r += __shfl_xor(r, off, 64);
            if (lr == 0) {
                int row = brow * 128 + wr * 64 + m * 16 + lk * 4 + j;
                atomicAdd(&rowsum[row], r);
            }
        }
    }
}

// ---------------- kernel 3: diag + logsumexp -> loss ----------------
__global__ __launch_bounds__(256) void loss_kernel(
    const unsigned short* __restrict__ qn, const unsigned short* __restrict__ dn,
    const float* __restrict__ rowsum, float* __restrict__ out) {
    int row = blockIdx.x;
    int t = threadIdx.x;
    uint2 ua = reinterpret_cast<const uint2*>(qn + (size_t)row * DIM)[t];
    uint2 ub = reinterpret_cast<const uint2*>(dn + (size_t)row * DIM)[t];
    float s = bf2f(ua.x) * bf2f(ub.x) + bf2f(ua.x >> 16) * bf2f(ub.x >> 16)
            + bf2f(ua.y) * bf2f(ub.y) + bf2f(ua.y >> 16) * bf2f(ub.y >> 16);
#pragma unroll
    for (int off = 32; off > 0; off >>= 1) s += __shfl_xor(s, off, 64);
    __shared__ float wsum[4];
    if ((t & 63) == 0) wsum[t >> 6] = s;
    __syncthreads();
    if (t == 0) {
        float diag = 20.f * (wsum[0] + wsum[1] + wsum[2] + wsum[3]);
        float lse = 20.f + __logf(rowsum[row]);   // lse of shifted sum
        atomicAdd(out, (lse - diag) * (1.0f / 4096.f));
    }
}

extern "C" void kernel_launch(void* const* d_in, const int* in_sizes, int n_in,
                              void* d_out, int out_size, void* d_ws, size_t ws_size,
                              hipStream_t stream) {
    const float* q   = (const float*)d_in[0];
    const float* pos = (const float*)d_in[1];
    const float* neg = (const float*)d_in[2];
    float* out = (float*)d_out;
    char* ws = (char*)d_ws;
    unsigned short* qn = (unsigned short*)ws;                                // 8 MB
    unsigned short* dn = (unsigned short*)(ws + (size_t)8 * 1024 * 1024);    // 16 MB
    float* rowsum = (float*)(ws + (size_t)24 * 1024 * 1024);                 // 16 KB

    hipMemsetAsync(rowsum, 0, NQ * sizeof(float), stream);
    hipMemsetAsync(out, 0, sizeof(float), stream);
    normalize_kernel<<<12288, 256, 0, stream>>>(q, pos, neg, qn, dn);
    gemm_lse_kernel<<<dim3(NDOC / 128, NQ / 128), 256, 0, stream>>>(qn, dn, rowsum);
    loss_kernel<<<NQ, 256, 0, stream>>>(qn, dn, rowsum, out);
}

// Round 2
// 249.436 us; speedup vs baseline: 1.0160x; 1.0160x over previous
//
#include <hip/hip_runtime.h>
#include <stdint.h>

typedef __attribute__((ext_vector_type(8))) short s16x8;
typedef __attribute__((ext_vector_type(4))) float f32x4;

#define DIM 1024
#define NQ 4096
#define NDOC 8192
#define BK 32
#define NT (DIM / BK)   // 32 K-tiles

__device__ __forceinline__ unsigned short f2bf(float f) {
    unsigned int u = __builtin_bit_cast(unsigned int, f);
    u += 0x7FFFu + ((u >> 16) & 1u);   // RNE
    return (unsigned short)(u >> 16);
}
__device__ __forceinline__ float bf2f(unsigned int s) {
    unsigned int u = (s & 0xFFFFu) << 16;
    return __builtin_bit_cast(float, u);
}

template<int N> __device__ __forceinline__ void wait_vm() {
    if constexpr (N == 8)      asm volatile("s_waitcnt vmcnt(8)" ::: "memory");
    else if constexpr (N == 4) asm volatile("s_waitcnt vmcnt(4)" ::: "memory");
    else                       asm volatile("s_waitcnt vmcnt(0)" ::: "memory");
}

// ---------------- kernel 1: L2-normalize rows, cast to bf16; also zero rowsum/out --------
__global__ __launch_bounds__(256) void normalize_kernel(
    const float* __restrict__ q, const float* __restrict__ pos,
    const float* __restrict__ neg, unsigned short* __restrict__ qn,
    unsigned short* __restrict__ dn, float* __restrict__ rowsum,
    float* __restrict__ out) {
    int row = blockIdx.x;
    if (threadIdx.x == 0 && row < NQ) rowsum[row] = 0.f;
    if (row == 0 && threadIdx.x == 1) out[0] = 0.f;
    const float* src;
    unsigned short* dst;
    if (row < 4096) { src = q + (size_t)row * DIM; dst = qn + (size_t)row * DIM; }
    else if (row < 8192) { src = pos + (size_t)(row - 4096) * DIM; dst = dn + (size_t)(row - 4096) * DIM; }
    else { src = neg + (size_t)(row - 8192) * DIM; dst = dn + (size_t)(row - 4096) * DIM; }
    int t = threadIdx.x;
    float4 v = reinterpret_cast<const float4*>(src)[t];
    float ss = v.x * v.x + v.y * v.y + v.z * v.z + v.w * v.w;
#pragma unroll
    for (int off = 32; off > 0; off >>= 1) ss += __shfl_xor(ss, off, 64);
    __shared__ float wsum[4];
    if ((t & 63) == 0) wsum[t >> 6] = ss;
    __syncthreads();
    float tot = wsum[0] + wsum[1] + wsum[2] + wsum[3];
    float inv = rsqrtf(tot);   // norms ~32, EPS=1e-8 irrelevant
    uint2 o;
    o.x = (unsigned)f2bf(v.x * inv) | ((unsigned)f2bf(v.y * inv) << 16);
    o.y = (unsigned)f2bf(v.z * inv) | ((unsigned)f2bf(v.w * inv) << 16);
    reinterpret_cast<uint2*>(dst)[t] = o;
}

// ---------------- kernel 2: 256x256 deep-pipelined GEMM + fused exp-sum ----------------
// LDS layout per buffer b (4 ring buffers):
//   A(b): elems [b*8192 .. +8192)           as [lk][256 rows][8]  (lk = k-slice 0..3)
//   B(b): elems [32768 + b*8192 .. +8192)   same
// ds_read_b128 of a fragment hits 8 dwords/bank (conflict-free floor).
// global_load_lds: dest = linear lane*16B; source pre-permuted per lane.
#define GLOAD_LDS(g, l) __builtin_amdgcn_global_load_lds( \
    (const __attribute__((address_space(1))) void*)(g),   \
    (__attribute__((address_space(3))) void*)(l), 16, 0, 0)

#define STAGE_A(b, kt) {                                              \
    const unsigned short* s_ = aSrc + (kt) * BK;                      \
    unsigned short* d_ = lds + (size_t)(b) * 8192 + tid * 8;          \
    GLOAD_LDS(s_, d_);                                                \
    GLOAD_LDS(s_ + 16, d_ + 4096);                                    \
  }
#define STAGE_B(b, kt) {                                              \
    const unsigned short* s_ = bSrc + (kt) * BK;                      \
    unsigned short* d_ = lds + 32768 + (size_t)(b) * 8192 + tid * 8;  \
    GLOAD_LDS(s_, d_);                                                \
    GLOAD_LDS(s_ + 16, d_ + 4096);                                    \
  }

// One K-tile: 2 phases, 16 MFMA each. Counted vmcnt at tile boundary only.
#define KBODY(b, ts, DOSTAGE, VMN)                                            \
  {                                                                           \
    s16x8 bF[4], aF[4];                                                       \
    _Pragma("unroll") for (int n = 0; n < 4; ++n)                             \
      bF[n] = *(const s16x8*)(bBase + (b) * 8192 + n * 128);                  \
    _Pragma("unroll") for (int m = 0; m < 4; ++m)                             \
      aF[m] = *(const s16x8*)(aBase + (b) * 8192 + m * 128);                  \
    if (DOSTAGE) { STAGE_A((ts) & 3, ts); }                                   \
    __builtin_amdgcn_s_barrier();                                             \
    asm volatile("s_waitcnt lgkmcnt(0)" ::: "memory");                        \
    __builtin_amdgcn_sched_barrier(0);                                        \
    __builtin_amdgcn_s_setprio(1);                                            \
    _Pragma("unroll") for (int m = 0; m < 4; ++m)                             \
      _Pragma("unroll") for (int n = 0; n < 4; ++n)                           \
        acc[m][n] = __builtin_amdgcn_mfma_f32_16x16x32_bf16(aF[m], bF[n], acc[m][n], 0, 0, 0); \
    __builtin_amdgcn_s_setprio(0);                                            \
    __builtin_amdgcn_s_barrier();                                             \
    _Pragma("unroll") for (int m = 0; m < 4; ++m)                             \
      aF[m] = *(const s16x8*)(aBase + (b) * 8192 + (m + 4) * 128);            \
    if (DOSTAGE) { STAGE_B((ts) & 3, ts); }                                   \
    __builtin_amdgcn_s_barrier();                                             \
    asm volatile("s_waitcnt lgkmcnt(0)" ::: "memory");                        \
    __builtin_amdgcn_sched_barrier(0);                                        \
    __builtin_amdgcn_s_setprio(1);                                            \
    _Pragma("unroll") for (int m = 0; m < 4; ++m)                             \
      _Pragma("unroll") for (int n = 0; n < 4; ++n)                           \
        acc[m + 4][n] = __builtin_amdgcn_mfma_f32_16x16x32_bf16(aF[m], bF[n], acc[m + 4][n], 0, 0, 0); \
    __builtin_amdgcn_s_setprio(0);                                            \
    wait_vm<VMN>();                                                           \
    __builtin_amdgcn_s_barrier();                                             \
  }

__global__ __launch_bounds__(512, 2) void gemm_lse_kernel(
    const unsigned short* __restrict__ qn, const unsigned short* __restrict__ dn,
    float* __restrict__ rowsum) {
    extern __shared__ unsigned short lds[];   // 131072 bytes
    const int tid = threadIdx.x;
    const int lane = tid & 63;
    const int wid = tid >> 6;
    const int wr = wid >> 2;        // 0..1  (128-row half)
    const int wc = wid & 3;         // 0..3  (64-col slice)
    const int lr = lane & 15;
    const int lk = lane >> 4;

    // XCD-aware blocked swizzle: each XCD owns an 8x8 tile region of the 16x32 grid
    int bid = blockIdx.x;
    int xcd = bid & 7, local = bid >> 3;
    int brow = (xcd >> 2) * 8 + (local >> 3);   // 0..15
    int bcol = (xcd & 3) * 8 + (local & 7);     // 0..31

    // staging: chunk c = r*512 + tid (r=0,1) -> lk = c>>8, row = c&255
    const int srow = tid & 255;
    const int slk0 = tid >> 8;      // 0..1 (round 1 adds +2)
    const unsigned short* aSrc = qn + (size_t)(brow * 256 + srow) * DIM + slk0 * 8;
    const unsigned short* bSrc = dn + (size_t)(bcol * 256 + srow) * DIM + slk0 * 8;

    // fragment read bases (elements)
    const unsigned short* aBase = lds + lk * 2048 + (wr * 128 + lr) * 8;
    const unsigned short* bBase = lds + 32768 + lk * 2048 + (wc * 64 + lr) * 8;

    f32x4 acc[8][4] = {};

    // prologue: stage K-tiles 0,1,2 (12 loads in flight)
    STAGE_A(0, 0); STAGE_B(0, 0);
    STAGE_A(1, 1); STAGE_B(1, 1);
    STAGE_A(2, 2); STAGE_B(2, 2);
    wait_vm<8>();                      // tile 0 complete (tiles 1,2 in flight)
    __builtin_amdgcn_s_barrier();

    for (int t = 0; t < NT - 3; ++t)   // t = 0..28: stage t+3, vmcnt(8)
        KBODY(t & 3, t + 3, true, 8);
    KBODY(29 & 3, 0, false, 4);        // t=29: younger={31} -> vmcnt(4)
    KBODY(30 & 3, 0, false, 0);        // t=30: drain
    KBODY(31 & 3, 0, false, 0);        // t=31: last

    // epilogue: rowsum[row] += sum_cols exp(20*s - 20)
    // C/D: col = lr, row_in_frag = lk*4 + j
#pragma unroll
    for (int m = 0; m < 8; ++m) {
#pragma unroll
        for (int j = 0; j < 4; ++j) {
            float r = 0.f;
#pragma unroll
            for (int n = 0; n < 4; ++n) {
                float s = 20.f * acc[m][n][j] - 20.f;
                r += __expf(s);
            }
#pragma unroll
            for (int off = 1; off < 16; off <<= 1) r += __shfl_xor(r, off, 64);
            if (lr == 0) {
                int row = brow * 256 + wr * 128 + m * 16 + lk * 4 + j;
                atomicAdd(&rowsum[row], r);
            }
        }
    }
}

// ---------------- kernel 3: diag + logsumexp -> loss ----------------
__global__ __launch_bounds__(256) void loss_kernel(
    const unsigned short* __restrict__ qn, const unsigned short* __restrict__ dn,
    const float* __restrict__ rowsum, float* __restrict__ out) {
    int row = blockIdx.x;
    int t = threadIdx.x;
    uint2 ua = reinterpret_cast<const uint2*>(qn + (size_t)row * DIM)[t];
    uint2 ub = reinterpret_cast<const uint2*>(dn + (size_t)row * DIM)[t];
    float s = bf2f(ua.x) * bf2f(ub.x) + bf2f(ua.x >> 16) * bf2f(ub.x >> 16)
            + bf2f(ua.y) * bf2f(ub.y) + bf2f(ua.y >> 16) * bf2f(ub.y >> 16);
#pragma unroll
    for (int off = 32; off > 0; off >>= 1) s += __shfl_xor(s, off, 64);
    __shared__ float wsum[4];
    if ((t & 63) == 0) wsum[t >> 6] = s;
    __syncthreads();
    if (t == 0) {
        float diag = 20.f * (wsum[0] + wsum[1] + wsum[2] + wsum[3]);
        float lse = 20.f + __logf(rowsum[row]);   // lse of shifted sum
        atomicAdd(out, (lse - diag) * (1.0f / 4096.f));
    }
}

extern "C" void kernel_launch(void* const* d_in, const int* in_sizes, int n_in,
                              void* d_out, int out_size, void* d_ws, size_t ws_size,
                              hipStream_t stream) {
    const float* q   = (const float*)d_in[0];
    const float* pos = (const float*)d_in[1];
    const float* neg = (const float*)d_in[2];
    float* out = (float*)d_out;
    char* ws = (char*)d_ws;
    unsigned short* qn = (unsigned short*)ws;                                // 8 MB
    unsigned short* dn = (unsigned short*)(ws + (size_t)8 * 1024 * 1024);    // 16 MB
    float* rowsum = (float*)(ws + (size_t)24 * 1024 * 1024);                 // 16 KB

    static bool attr_set = false;
    if (!attr_set) {
        (void)hipFuncSetAttribute((const void*)gemm_lse_kernel,
                                  hipFuncAttributeMaxDynamicSharedMemorySize, 131072);
        attr_set = true;
    }

    normalize_kernel<<<12288, 256, 0, stream>>>(q, pos, neg, qn, dn, rowsum, out);
    gemm_lse_kernel<<<512, 512, 131072, stream>>>(qn, dn, rowsum);
    loss_kernel<<<NQ, 256, 0, stream>>>(qn, dn, rowsum, out);
}

// Round 3
// 208.477 us; speedup vs baseline: 1.2156x; 1.1965x over previous
//
#include <hip/hip_runtime.h>
#include <stdint.h>

typedef __attribute__((ext_vector_type(8))) short s16x8;
typedef __attribute__((ext_vector_type(4))) float f32x4;

#define DIM 1024
#define NQ 4096
#define NDOC 8192
#define BK 32
#define NT 32

__device__ __forceinline__ unsigned f2bf(float f) {
    unsigned int u = __builtin_bit_cast(unsigned int, f);
    u += 0x7FFFu + ((u >> 16) & 1u);   // RNE
    return u >> 16;
}
__device__ __forceinline__ float bf2f(unsigned int s) {
    unsigned int u = (s & 0xFFFFu) << 16;
    return __builtin_bit_cast(float, u);
}

// asm LDS read: compiler-blind (prevents hidden protective vmcnt/lgkm waits)
__device__ __forceinline__ s16x8 lds_read16(unsigned byte_off) {
    s16x8 r;
    asm volatile("ds_read_b128 %0, %1" : "=v"(r) : "v"(byte_off));
    return r;
}
__device__ __forceinline__ unsigned lds_off(const unsigned short* p) {
    return (unsigned)(uintptr_t)(__attribute__((address_space(3))) const unsigned short*)p;
}
template<int N> __device__ __forceinline__ void wait_vm() {
    if constexpr (N == 8)      asm volatile("s_waitcnt vmcnt(8)" ::: "memory");
    else if constexpr (N == 4) asm volatile("s_waitcnt vmcnt(4)" ::: "memory");
    else                       asm volatile("s_waitcnt vmcnt(0)" ::: "memory");
}

// ---------------- kernel 1: L2-normalize rows -> bf16 (one wave per row) ----------------
__global__ __launch_bounds__(256) void normalize_kernel(
    const float* __restrict__ q, const float* __restrict__ pos,
    const float* __restrict__ neg, unsigned short* __restrict__ qn,
    unsigned short* __restrict__ dn, float* __restrict__ rowsum) {
    int row = blockIdx.x * 4 + (threadIdx.x >> 6);
    int lane = threadIdx.x & 63;
    const float* src;
    unsigned short* dst;
    if (row < 4096) {
        src = q + (size_t)row * DIM; dst = qn + (size_t)row * DIM;
        if (lane == 0) rowsum[row] = 0.f;
    } else if (row < 8192) {
        src = pos + (size_t)(row - 4096) * DIM; dst = dn + (size_t)(row - 4096) * DIM;
    } else {
        src = neg + (size_t)(row - 8192) * DIM; dst = dn + (size_t)(row - 4096) * DIM;
    }
    float4 v[4];
    float ss = 0.f;
#pragma unroll
    for (int it = 0; it < 4; ++it) {
        v[it] = reinterpret_cast<const float4*>(src)[it * 64 + lane];
        ss += v[it].x * v[it].x + v[it].y * v[it].y + v[it].z * v[it].z + v[it].w * v[it].w;
    }
#pragma unroll
    for (int off = 32; off > 0; off >>= 1) ss += __shfl_xor(ss, off, 64);
    float inv = rsqrtf(ss);   // norms ~32, EPS=1e-8 irrelevant
#pragma unroll
    for (int it = 0; it < 4; ++it) {
        uint2 o;
        o.x = f2bf(v[it].x * inv) | (f2bf(v[it].y * inv) << 16);
        o.y = f2bf(v[it].z * inv) | (f2bf(v[it].w * inv) << 16);
        reinterpret_cast<uint2*>(dst)[it * 64 + lane] = o;
    }
}

// ---------------- kernel 2: 256x256 GEMM + fused exp-sum, asm-scheduled ----------------
// LDS (128 KB): 4 ring buffers of 32 KB. Buffer b:
//   A: bytes [b*32768 .. +16384)  laid out [lk 0..3][row 0..255][8 elems] (16B units)
//   B: bytes [b*32768+16384 .. +32768) same.
// Frag read (conflict-free floor): byte = base + lk*4096 + row*16.
// Staging dest is linear in tid*16 (gload_lds constraint); source k-slice pre-permuted.
#define GLOAD_LDS(g, l) __builtin_amdgcn_global_load_lds( \
    (const __attribute__((address_space(1))) void*)(g),   \
    (__attribute__((address_space(3))) void*)(l), 16, 0, 0)

#define STAGE_A(b, kt) {                                                     \
    const unsigned short* s_ = aSrc + (kt) * BK;                             \
    unsigned short* d_ = lds + (unsigned)(b) * 16384u + (unsigned)tid * 8u;  \
    GLOAD_LDS(s_, d_);                                                       \
    GLOAD_LDS(s_ + 16, d_ + 4096);                                           \
  }
#define STAGE_B(b, kt) {                                                     \
    const unsigned short* s_ = bSrc + (kt) * BK;                             \
    unsigned short* d_ = lds + (unsigned)(b) * 16384u + 8192u + (unsigned)tid * 8u; \
    GLOAD_LDS(s_, d_);                                                       \
    GLOAD_LDS(s_ + 16, d_ + 4096);                                           \
  }

// One K-tile = 2 phases x 16 MFMA. All 12 ds_reads issued up front;
// lgkmcnt(4) releases phase 1 (first 8 reads), lgkmcnt(0) phase 2.
// Counted vmcnt(VMN) once per tile. Raw barriers only.
#define TILE(b, ts, DOSTAGE, VMN) {                                          \
    s16x8 aF[8], bF[4];                                                      \
    _Pragma("unroll") for (int n = 0; n < 4; ++n)                            \
        bF[n] = lds_read16(bOff + (unsigned)(b) * 32768u + n * 256u);        \
    _Pragma("unroll") for (int m = 0; m < 8; ++m)                            \
        aF[m] = lds_read16(aOff + (unsigned)(b) * 32768u + m * 256u);        \
    if (DOSTAGE) STAGE_A((ts) & 3, ts);                                      \
    __builtin_amdgcn_s_barrier();                                            \
    asm volatile("s_waitcnt lgkmcnt(4)" ::: "memory");                       \
    __builtin_amdgcn_sched_barrier(0);                                       \
    __builtin_amdgcn_s_setprio(1);                                           \
    _Pragma("unroll") for (int m = 0; m < 4; ++m)                            \
        _Pragma("unroll") for (int n = 0; n < 4; ++n)                        \
            acc[m][n] = __builtin_amdgcn_mfma_f32_16x16x32_bf16(aF[m], bF[n], acc[m][n], 0, 0, 0); \
    __builtin_amdgcn_s_setprio(0);                                           \
    __builtin_amdgcn_s_barrier();                                            \
    if (DOSTAGE) STAGE_B((ts) & 3, ts);                                      \
    asm volatile("s_waitcnt lgkmcnt(0)" ::: "memory");                       \
    __builtin_amdgcn_sched_barrier(0);                                       \
    __builtin_amdgcn_s_setprio(1);                                           \
    _Pragma("unroll") for (int m = 0; m < 4; ++m)                            \
        _Pragma("unroll") for (int n = 0; n < 4; ++n)                        \
            acc[m + 4][n] = __builtin_amdgcn_mfma_f32_16x16x32_bf16(aF[m + 4], bF[n], acc[m + 4][n], 0, 0, 0); \
    __builtin_amdgcn_s_setprio(0);                                           \
    wait_vm<VMN>();                                                          \
    __builtin_amdgcn_sched_barrier(0);                                       \
    __builtin_amdgcn_s_barrier();                                            \
  }

__global__ __launch_bounds__(512, 2) void gemm_lse_kernel(
    const unsigned short* __restrict__ qn, const unsigned short* __restrict__ dn,
    float* __restrict__ rowsum) {
    extern __shared__ unsigned short lds[];   // 131072 bytes
    const int tid = threadIdx.x;
    const int lane = tid & 63;
    const int wid = tid >> 6;
    const int wr = wid >> 2;        // 0..1  (128-row half)
    const int wc = wid & 3;         // 0..3  (64-col slice)
    const int lr = lane & 15;
    const int lk = lane >> 4;

    // XCD-aware blocked swizzle: each XCD owns an 8x8 region of the 16x32 grid
    int bid = blockIdx.x;
    int xcd = bid & 7, local = bid >> 3;
    int brow = (xcd >> 2) * 8 + (local >> 3);   // 0..15
    int bcol = (xcd & 3) * 8 + (local & 7);     // 0..31

    const int srow = tid & 255;
    const int slk0 = tid >> 8;      // 0..1 (second gload adds +2 slices)
    const unsigned short* aSrc = qn + (size_t)(brow * 256 + srow) * DIM + slk0 * 8;
    const unsigned short* bSrc = dn + (size_t)(bcol * 256 + srow) * DIM + slk0 * 8;

    const unsigned ldsBase = lds_off(lds);
    const unsigned aOff = ldsBase + lk * 4096u + (wr * 128 + lr) * 16u;
    const unsigned bOff = ldsBase + 16384u + lk * 4096u + (wc * 64 + lr) * 16u;

    f32x4 acc[8][4] = {};

    // prologue: stage K-tiles 0,1,2 (12 loads); tile 0 landed before barrier
    STAGE_A(0, 0); STAGE_B(0, 0);
    STAGE_A(1, 1); STAGE_B(1, 1);
    STAGE_A(2, 2); STAGE_B(2, 2);
    wait_vm<8>();
    __builtin_amdgcn_sched_barrier(0);
    __builtin_amdgcn_s_barrier();

#pragma unroll
    for (int t = 0; t < NT - 3; ++t)    // t=0..28: stage t+3, keep 8 in flight
        TILE(t & 3, t + 3, true, 8);
    TILE(29 & 3, 0, false, 4);          // tile 30 landed
    TILE(30 & 3, 0, false, 0);          // drain
    TILE(31 & 3, 0, false, 0);          // last (no-op waits)

    // epilogue: rowsum[row] += sum_cols exp(20*s - 20)
    // C/D: col = lr, row_in_frag = lk*4 + j
#pragma unroll
    for (int m = 0; m < 8; ++m) {
#pragma unroll
        for (int j = 0; j < 4; ++j) {
            float r = 0.f;
#pragma unroll
            for (int n = 0; n < 4; ++n) {
                float s = 20.f * acc[m][n][j] - 20.f;
                r += __expf(s);
            }
#pragma unroll
            for (int off = 1; off < 16; off <<= 1) r += __shfl_xor(r, off, 64);
            if (lr == 0) {
                int row = brow * 256 + wr * 128 + m * 16 + lk * 4 + j;
                atomicAdd(&rowsum[row], r);
            }
        }
    }
}

// ---------------- kernel 3: per-row diag + lse (one wave per row, no atomics) -----------
__global__ __launch_bounds__(256) void loss_kernel(
    const unsigned short* __restrict__ qn, const unsigned short* __restrict__ dn,
    const float* __restrict__ rowsum, float* __restrict__ rowloss) {
    int row = blockIdx.x * 4 + (threadIdx.x >> 6);
    int lane = threadIdx.x & 63;
    const uint4* a4 = reinterpret_cast<const uint4*>(qn + (size_t)row * DIM);
    const uint4* b4 = reinterpret_cast<const uint4*>(dn + (size_t)row * DIM);
    float s = 0.f;
#pragma unroll
    for (int it = 0; it < 2; ++it) {
        uint4 ua = a4[it * 64 + lane], ub = b4[it * 64 + lane];
        s += bf2f(ua.x) * bf2f(ub.x) + bf2f(ua.x >> 16) * bf2f(ub.x >> 16);
        s += bf2f(ua.y) * bf2f(ub.y) + bf2f(ua.y >> 16) * bf2f(ub.y >> 16);
        s += bf2f(ua.z) * bf2f(ub.z) + bf2f(ua.z >> 16) * bf2f(ub.z >> 16);
        s += bf2f(ua.w) * bf2f(ub.w) + bf2f(ua.w >> 16) * bf2f(ub.w >> 16);
    }
#pragma unroll
    for (int off = 32; off > 0; off >>= 1) s += __shfl_xor(s, off, 64);
    if (lane == 0)
        rowloss[row] = (20.f + __logf(rowsum[row])) - 20.f * s;
}

// ---------------- kernel 4: mean over 4096 row losses ----------------
__global__ __launch_bounds__(1024) void reduce_kernel(
    const float* __restrict__ rowloss, float* __restrict__ out) {
    int t = threadIdx.x;
    float s = 0.f;
#pragma unroll
    for (int i = 0; i < 4; ++i) s += rowloss[t + i * 1024];
#pragma unroll
    for (int off = 32; off > 0; off >>= 1) s += __shfl_xor(s, off, 64);
    __shared__ float wsum[16];
    if ((t & 63) == 0) wsum[t >> 6] = s;
    __syncthreads();
    if (t == 0) {
        float tot = 0.f;
#pragma unroll
        for (int i = 0; i < 16; ++i) tot += wsum[i];
        out[0] = tot * (1.f / 4096.f);
    }
}

extern "C" void kernel_launch(void* const* d_in, const int* in_sizes, int n_in,
                              void* d_out, int out_size, void* d_ws, size_t ws_size,
                              hipStream_t stream) {
    const float* q   = (const float*)d_in[0];
    const float* pos = (const float*)d_in[1];
    const float* neg = (const float*)d_in[2];
    float* out = (float*)d_out;
    char* ws = (char*)d_ws;
    unsigned short* qn = (unsigned short*)ws;                                 // 8 MB
    unsigned short* dn = (unsigned short*)(ws + (size_t)8 * 1024 * 1024);     // 16 MB
    float* rowsum  = (float*)(ws + (size_t)24 * 1024 * 1024);                 // 16 KB
    float* rowloss = (float*)(ws + (size_t)24 * 1024 * 1024 + 16384);         // 16 KB

    static bool attr_set = false;
    if (!attr_set) {
        (void)hipFuncSetAttribute((const void*)gemm_lse_kernel,
                                  hipFuncAttributeMaxDynamicSharedMemorySize, 131072);
        attr_set = true;
    }

    normalize_kernel<<<3072, 256, 0, stream>>>(q, pos, neg, qn, dn, rowsum);
    gemm_lse_kernel<<<512, 512, 131072, stream>>>(qn, dn, rowsum);
    loss_kernel<<<1024, 256, 0, stream>>>(qn, dn, rowsum, rowloss);
    reduce_kernel<<<1, 1024, 0, stream>>>(rowloss, out);
}